// Round 6
// baseline (66.095 us; speedup 1.0000x reference)
//
#include <hip/hip_runtime.h>
#include <math.h>

// Problem constants
#define B_  32
#define C_  256
#define H_  56
#define W_  56
#define CR_ 64          // C/RED
#define HW_ (H_*W_)     // 3136
#define BC_ (B_*C_)     // 8192

#define SMS  68         // LDS row stride in floats (16B-aligned, bank-spread)
#define SMS4 17         // .. in float4

// ---------------------------------------------------------------------------
// Kernel 1: global average pool. One block per (b,c) plane. HBM-read bound.
// ---------------------------------------------------------------------------
__global__ __launch_bounds__(256) void gap_kernel(const float* __restrict__ x,
                                                  float* __restrict__ gap) {
    const int bc = blockIdx.x;
    const float4* p4 = (const float4*)(x + (size_t)bc * HW_);
    float s = 0.f;
    for (int i = threadIdx.x; i < HW_ / 4; i += 256) {
        float4 v = p4[i];
        s += (v.x + v.y) + (v.z + v.w);
    }
    for (int off = 32; off > 0; off >>= 1) s += __shfl_down(s, off, 64);
    __shared__ float ws[4];
    const int lane = threadIdx.x & 63, wid = threadIdx.x >> 6;
    if (lane == 0) ws[wid] = s;
    __syncthreads();
    if (threadIdx.x == 0) {
        float t = (ws[0] + ws[1]) + (ws[2] + ws[3]);
        gap[bc] = t * (1.0f / (float)HW_);
    }
}

// ---------------------------------------------------------------------------
// Kernel 2: hid = gelu(gap @ w1^T + b1). One block (256 thr) per batch;
// 4 lanes cooperate per output channel (16 float4 each + shfl reduce).
// ---------------------------------------------------------------------------
__global__ __launch_bounds__(256) void hid_kernel(const float* __restrict__ gap,
                                                  const float* __restrict__ w1,
                                                  const float* __restrict__ b1,
                                                  float* __restrict__ hid_g) {
    const int b = blockIdx.x;
    const int j = threadIdx.x >> 2;      // output channel 0..63
    const int part = threadIdx.x & 3;    // quarter 0..3
    const float4* wr = (const float4*)(w1 + (size_t)j * C_) + part * 16;
    const float4* gv = (const float4*)(gap + (size_t)b * C_) + part * 16;
    float acc = 0.f;
    #pragma unroll
    for (int q = 0; q < 16; ++q) {
        float4 w = wr[q], g = gv[q];
        acc += w.x * g.x + w.y * g.y + w.z * g.z + w.w * g.w;
    }
    acc += __shfl_xor(acc, 1, 64);
    acc += __shfl_xor(acc, 2, 64);
    if (part == 0) {
        acc += b1[j];
        hid_g[b * CR_ + j] = 0.5f * acc * (1.0f + erff(acc * 0.7071067811865476f));
    }
}

// ---------------------------------------------------------------------------
// Kernel 3: fused logits + softmax + dynamic 3x3 depthwise conv + residual.
// One 128-thread block per (b,c) plane. LDS 58 rows x 68-float stride,
// halo-only zero-fill (disjoint ADDRESSES from staging -> ONE barrier;
// threads may do several fill jobs). Thread = (7-row strip, 4-col group):
// rolling registers, per new row one ds_read_b128 + 2 scalar halo reads;
// float4 stores.
// ---------------------------------------------------------------------------
__global__ __launch_bounds__(128) void dconv_kernel(const float* __restrict__ x,
                                                    const float* __restrict__ hid_g,
                                                    const float* __restrict__ w2,
                                                    const float* __restrict__ b2,
                                                    float* __restrict__ out) {
    const int bc = blockIdx.x;
    const int b  = bc >> 8;
    const int c  = bc & 255;
    const float* p = x + (size_t)bc * HW_;
    float* o = out + (size_t)bc * HW_;

    // LDS rows 0..57 = image rows -1..56; image col xw -> LDS col xw+4.
    // Zero halo: rows {0,57} (full), cols {3,60} rows 1..56.
    __shared__ float sm[58 * SMS];
    __shared__ float lgs[9];
    float4* sm4 = (float4*)sm;
    const int tid = threadIdx.x;

    // halo zero fill — two INDEPENDENT jobs (128 threads cover both):
    // job A: rows 0 and 57, full width as float4 (34 workers)
    if (tid < 34) {
        const int r = (tid & 1) ? 57 : 0;
        sm4[r * SMS4 + (tid >> 1)] = make_float4(0.f, 0.f, 0.f, 0.f);
    }
    // job B: side cols 3 and 60, rows 1..56 (112 workers)
    if (tid < 112) {
        sm[(1 + (tid >> 1)) * SMS + ((tid & 1) ? 60 : 3)] = 0.f;
    }

    // this channel's 9 logits (lanes 0..8), overlapped with staging
    if (tid < 9) {
        const float4* wr = (const float4*)(w2 + ((size_t)c * 9 + tid) * CR_);
        const float4* hv = (const float4*)(hid_g + (size_t)b * CR_);
        float acc = b2[c * 9 + tid];
        #pragma unroll
        for (int q = 0; q < 16; ++q) {
            float4 w = wr[q], h = hv[q];
            acc += w.x * h.x + w.y * h.y + w.z * h.z + w.w * h.w;
        }
        lgs[tid] = acc;
    }

    // interior stage: image rows 0..55 -> LDS rows 1..56, cols 4..59
    const float4* p4 = (const float4*)p;
    for (int i = tid; i < HW_ / 4; i += 128) {
        const int y = i / 14, q = i - y * 14;
        sm4[(y + 1) * SMS4 + 1 + q] = p4[i];
    }
    __syncthreads();

    // redundant per-thread softmax over the 9 taps (LDS broadcasts)
    float l0 = lgs[0], l1 = lgs[1], l2 = lgs[2], l3 = lgs[3], l4 = lgs[4],
          l5 = lgs[5], l6 = lgs[6], l7 = lgs[7], l8 = lgs[8];
    float mx = fmaxf(fmaxf(fmaxf(fmaxf(l0, l1), fmaxf(l2, l3)),
                           fmaxf(fmaxf(l4, l5), fmaxf(l6, l7))), l8);
    float k0 = __expf(l0 - mx), k1 = __expf(l1 - mx), k2 = __expf(l2 - mx),
          k3 = __expf(l3 - mx), k4 = __expf(l4 - mx), k5 = __expf(l5 - mx),
          k6 = __expf(l6 - mx), k7 = __expf(l7 - mx), k8 = __expf(l8 - mx);
    const float inv = 1.0f / (((k0 + k1) + (k2 + k3)) + ((k4 + k5) + (k6 + k7)) + k8);
    k0 *= inv; k1 *= inv; k2 *= inv; k3 *= inv; k4 *= inv;
    k5 *= inv; k6 *= inv; k7 *= inv; k8 *= inv;

    // conv: thread = (strip s: 7 rows, col-group cg: 4 cols); 112 active
    if (tid < 112) {
        const int s  = tid / 14;
        const int cg = tid - s * 14;
        const int y0 = s * 7;                       // first output row
        const float* base = sm + y0 * SMS + 4 + 4 * cg;  // LDS row y0 = image row y0-1

        float4 A  = *(const float4*)(base);         // row y0-1
        float La = base[-1], Ra = base[4];
        const float* r1 = base + SMS;               // row y0
        float4 Bv = *(const float4*)(r1);
        float Lb = r1[-1], Rb = r1[4];

        #pragma unroll
        for (int r = 0; r < 7; ++r) {
            const float* r2 = base + (r + 2) * SMS; // row y0+r+1
            const float4 Cv = *(const float4*)(r2);
            const float Lc = r2[-1], Rc = r2[4];

            const float o0 = La  * k0 + A.x * k1 + A.y * k2
                           + Lb  * k3 + Bv.x * k4 + Bv.y * k5
                           + Lc  * k6 + Cv.x * k7 + Cv.y * k8 + Bv.x;
            const float o1 = A.x * k0 + A.y * k1 + A.z * k2
                           + Bv.x * k3 + Bv.y * k4 + Bv.z * k5
                           + Cv.x * k6 + Cv.y * k7 + Cv.z * k8 + Bv.y;
            const float o2 = A.y * k0 + A.z * k1 + A.w * k2
                           + Bv.y * k3 + Bv.z * k4 + Bv.w * k5
                           + Cv.y * k6 + Cv.z * k7 + Cv.w * k8 + Bv.z;
            const float o3 = A.z * k0 + A.w * k1 + Ra  * k2
                           + Bv.z * k3 + Bv.w * k4 + Rb  * k5
                           + Cv.z * k6 + Cv.w * k7 + Rc  * k8 + Bv.w;

            *(float4*)(o + (y0 + r) * W_ + 4 * cg) = make_float4(o0, o1, o2, o3);

            A = Bv; La = Lb; Ra = Rb;
            Bv = Cv; Lb = Lc; Rb = Rc;
        }
    }
}

// ---------------------------------------------------------------------------
extern "C" void kernel_launch(void* const* d_in, const int* in_sizes, int n_in,
                              void* d_out, int out_size, void* d_ws, size_t ws_size,
                              hipStream_t stream) {
    const float* x  = (const float*)d_in[0];
    const float* w1 = (const float*)d_in[1];
    const float* b1 = (const float*)d_in[2];
    const float* w2 = (const float*)d_in[3];
    const float* b2 = (const float*)d_in[4];
    float* out = (float*)d_out;

    float* gap   = (float*)d_ws;                 // 8192 floats
    float* hid_g = gap + BC_;                    // 32*64 = 2048 floats

    gap_kernel<<<BC_, 256, 0, stream>>>(x, gap);
    hid_kernel<<<B_, 256, 0, stream>>>(gap, w1, b1, hid_g);
    dconv_kernel<<<BC_, 128, 0, stream>>>(x, hid_g, w2, b2, out);
}

// Round 7
// 61.040 us; speedup vs baseline: 1.0828x; 1.0828x over previous
//
#include <hip/hip_runtime.h>
#include <math.h>

// Problem constants
#define B_  32
#define C_  256
#define H_  56
#define W_  56
#define CR_ 64          // C/RED
#define HW_ (H_*W_)     // 3136
#define BC_ (B_*C_)     // 8192

typedef float float2v __attribute__((ext_vector_type(2)));

// packed f32 FMA: d = a*b + c  (2 lanes of f32 per instruction)
__device__ __forceinline__ float2v pk_fma(float2v a, float2v b, float2v c) {
    float2v d;
    asm("v_pk_fma_f32 %0, %1, %2, %3" : "=v"(d) : "v"(a), "v"(b), "v"(c));
    return d;
}

// ---------------------------------------------------------------------------
// Kernel 1: global average pool. One block per (b,c) plane. HBM-read bound.
// ---------------------------------------------------------------------------
__global__ __launch_bounds__(256) void gap_kernel(const float* __restrict__ x,
                                                  float* __restrict__ gap) {
    const int bc = blockIdx.x;
    const float4* p4 = (const float4*)(x + (size_t)bc * HW_);
    float s = 0.f;
    for (int i = threadIdx.x; i < HW_ / 4; i += 256) {
        float4 v = p4[i];
        s += (v.x + v.y) + (v.z + v.w);
    }
    for (int off = 32; off > 0; off >>= 1) s += __shfl_down(s, off, 64);
    __shared__ float ws[4];
    const int lane = threadIdx.x & 63, wid = threadIdx.x >> 6;
    if (lane == 0) ws[wid] = s;
    __syncthreads();
    if (threadIdx.x == 0) {
        float t = (ws[0] + ws[1]) + (ws[2] + ws[3]);
        gap[bc] = t * (1.0f / (float)HW_);
    }
}

// ---------------------------------------------------------------------------
// Kernel 2: hid = gelu(gap @ w1^T + b1). One block (256 thr) per batch;
// 4 lanes cooperate per output channel (16 float4 each + shfl reduce).
// ---------------------------------------------------------------------------
__global__ __launch_bounds__(256) void hid_kernel(const float* __restrict__ gap,
                                                  const float* __restrict__ w1,
                                                  const float* __restrict__ b1,
                                                  float* __restrict__ hid_g) {
    const int b = blockIdx.x;
    const int j = threadIdx.x >> 2;      // output channel 0..63
    const int part = threadIdx.x & 3;    // quarter 0..3
    const float4* wr = (const float4*)(w1 + (size_t)j * C_) + part * 16;
    const float4* gv = (const float4*)(gap + (size_t)b * C_) + part * 16;
    float acc = 0.f;
    #pragma unroll
    for (int q = 0; q < 16; ++q) {
        float4 w = wr[q], g = gv[q];
        acc += w.x * g.x + w.y * g.y + w.z * g.z + w.w * g.w;
    }
    acc += __shfl_xor(acc, 1, 64);
    acc += __shfl_xor(acc, 2, 64);
    if (part == 0) {
        acc += b1[j];
        hid_g[b * CR_ + j] = 0.5f * acc * (1.0f + erff(acc * 0.7071067811865476f));
    }
}

// ---------------------------------------------------------------------------
// Kernel 3: fused logits + softmax + dynamic 3x3 depthwise conv + residual.
// One 256-thread block per (b,c) plane (geometry of the measured-best R3
// kernel: 8 blocks/CU, 32 waves/CU). LDS 58x64, halo-only zero-fill, ONE
// barrier. Conv: thread = (7-row strip, 2-col pair); 9 taps as 9
// v_pk_fma_f32 (packed f32, 2 outputs/instr) + packed residual; float2
// stores. 224/256 lanes active in conv.
// ---------------------------------------------------------------------------
__global__ __launch_bounds__(256) void dconv_kernel(const float* __restrict__ x,
                                                    const float* __restrict__ hid_g,
                                                    const float* __restrict__ w2,
                                                    const float* __restrict__ b2,
                                                    float* __restrict__ out) {
    const int bc = blockIdx.x;
    const int b  = bc >> 8;
    const int c  = bc & 255;
    const float* p = x + (size_t)bc * HW_;
    float* o = out + (size_t)bc * HW_;

    // LDS rows 0..57 = image rows -1..56; image col xw -> LDS col xw+4.
    // Read cols are 3..60; halo = rows {0,57} cols 3..60, cols {3,60} rows 1..56.
    __shared__ float sm[58 * 64];
    __shared__ float lgs[9];
    float4* sm4 = (float4*)sm;
    const int tid = threadIdx.x;

    // halo-only zero fill (228 workers, disjoint from interior)
    if (tid < 116) {
        const int r = (tid & 1) ? 57 : 0;
        sm[r * 64 + 3 + (tid >> 1)] = 0.f;
    } else if (tid < 228) {
        const int i = tid - 116;
        sm[(1 + (i >> 1)) * 64 + ((i & 1) ? 60 : 3)] = 0.f;
    }

    // this channel's 9 logits (lanes 0..8), overlapped with staging
    if (tid < 9) {
        const float4* wr = (const float4*)(w2 + ((size_t)c * 9 + tid) * CR_);
        const float4* hv = (const float4*)(hid_g + (size_t)b * CR_);
        float acc = b2[c * 9 + tid];
        #pragma unroll
        for (int q = 0; q < 16; ++q) {
            float4 w = wr[q], h = hv[q];
            acc += w.x * h.x + w.y * h.y + w.z * h.z + w.w * h.w;
        }
        lgs[tid] = acc;
    }

    // interior stage: image rows 0..55 -> LDS rows 1..56, cols 4..59
    const float4* p4 = (const float4*)p;
    for (int i = tid; i < HW_ / 4; i += 256) {
        const int y = i / 14, q = i - y * 14;
        sm4[(y + 1) * 16 + 1 + q] = p4[i];
    }
    __syncthreads();

    // redundant per-thread softmax over the 9 taps (LDS broadcasts)
    float l0 = lgs[0], l1 = lgs[1], l2 = lgs[2], l3 = lgs[3], l4 = lgs[4],
          l5 = lgs[5], l6 = lgs[6], l7 = lgs[7], l8 = lgs[8];
    float mx = fmaxf(fmaxf(fmaxf(fmaxf(l0, l1), fmaxf(l2, l3)),
                           fmaxf(fmaxf(l4, l5), fmaxf(l6, l7))), l8);
    float k0 = __expf(l0 - mx), k1 = __expf(l1 - mx), k2 = __expf(l2 - mx),
          k3 = __expf(l3 - mx), k4 = __expf(l4 - mx), k5 = __expf(l5 - mx),
          k6 = __expf(l6 - mx), k7 = __expf(l7 - mx), k8 = __expf(l8 - mx);
    const float inv = 1.0f / (((k0 + k1) + (k2 + k3)) + ((k4 + k5) + (k6 + k7)) + k8);
    k0 *= inv; k1 *= inv; k2 *= inv; k3 *= inv; k4 *= inv;
    k5 *= inv; k6 *= inv; k7 *= inv; k8 *= inv;

    // packed tap weights (both halves identical)
    const float2v K0 = {k0, k0}, K1 = {k1, k1}, K2 = {k2, k2};
    const float2v K3 = {k3, k3}, K4 = {k4, k4}, K5 = {k5, k5};
    const float2v K6 = {k6, k6}, K7 = {k7, k7}, K8 = {k8, k8};

    // conv: thread = (strip s: 7 rows, col-pair g: image cols 2g,2g+1)
    if (tid < 224) {
        const int s  = tid / 28;                 // strip 0..7
        const int g  = tid - s * 28;             // col-pair 0..27
        const int y0 = s * 7;                    // first output row
        // LDS col of image col (2g-1) = 2g+3
        const float* base = sm + y0 * 64 + 3 + 2 * g;   // LDS row y0 = image row y0-1

        // rolling rows: A = image row y0-1, B = image row y0 (4 scalars each)
        float a0 = base[0], a1 = base[1], a2 = base[2], a3 = base[3];
        const float* rB = base + 64;
        float b0 = rB[0], b1 = rB[1], b2 = rB[2], b3 = rB[3];

        #pragma unroll
        for (int r = 0; r < 7; ++r) {
            const float* rC = base + (r + 2) * 64;       // image row y0+r+1
            const float c0v = rC[0], c1v = rC[1], c2v = rC[2], c3v = rC[3];

            const float2v Am = {a0, a1}, A0 = {a1, a2}, Ap = {a2, a3};
            const float2v Bm = {b0, b1}, B0 = {b1, b2}, Bp = {b2, b3};
            const float2v Cm = {c0v, c1v}, C0 = {c1v, c2v}, Cp = {c2v, c3v};

            float2v acc = B0;                    // residual (center = input)
            acc = pk_fma(K0, Am, acc);
            acc = pk_fma(K1, A0, acc);
            acc = pk_fma(K2, Ap, acc);
            acc = pk_fma(K3, Bm, acc);
            acc = pk_fma(K4, B0, acc);
            acc = pk_fma(K5, Bp, acc);
            acc = pk_fma(K6, Cm, acc);
            acc = pk_fma(K7, C0, acc);
            acc = pk_fma(K8, Cp, acc);

            *(float2v*)(o + (y0 + r) * W_ + 2 * g) = acc;

            a0 = b0; a1 = b1; a2 = b2; a3 = b3;
            b0 = c0v; b1 = c1v; b2 = c2v; b3 = c3v;
        }
    }
}

// ---------------------------------------------------------------------------
extern "C" void kernel_launch(void* const* d_in, const int* in_sizes, int n_in,
                              void* d_out, int out_size, void* d_ws, size_t ws_size,
                              hipStream_t stream) {
    const float* x  = (const float*)d_in[0];
    const float* w1 = (const float*)d_in[1];
    const float* b1 = (const float*)d_in[2];
    const float* w2 = (const float*)d_in[3];
    const float* b2 = (const float*)d_in[4];
    float* out = (float*)d_out;

    float* gap   = (float*)d_ws;                 // 8192 floats
    float* hid_g = gap + BC_;                    // 32*64 = 2048 floats

    gap_kernel<<<BC_, 256, 0, stream>>>(x, gap);
    hid_kernel<<<B_, 256, 0, stream>>>(gap, w1, b1, hid_g);
    dconv_kernel<<<BC_, 256, 0, stream>>>(x, hid_g, w2, b2, out);
}